// Round 8
// baseline (410.687 us; speedup 1.0000x reference)
//
#include <hip/hip_runtime.h>
#include <hip/hip_bf16.h>

// ReBASED attention R11: split-K over heavy q-tiles + in-kernel flag merge.
// R10 post-mortem: balancing per-CU iteration SUM changed nothing -> makespan
// is longest-block-bound (qt=15 tile = 32 serial k-iters). setprio reverted
// (T5 is null/harmful in 2-barrier lockstep structures, m190).
// R11: tiles qt>=8 split into part0 kt[0,qt] / part1 kt[qt+1,2qt+1] -- every
// block now <= 16 serial k-iters; grid 1536 = 4 resident + 2 backfill per CU.
// Merge without a 3rd kernel: part0 writes unnormalized partial to og, part1
// to workspace; per-tile atomic flag (threadfence release/acquire); the block
// arriving SECOND merges partner data with its own in-register accumulators
// and normalizes. Both parts share a head -> same XCD -> exchange is L2-local.
// Flags zeroed by the convert pre-pass (same stream, runs first).
// Runtime ws_size guard: falls back to R9 mapping (nsplit=0) if ws < 50.9MB.
// Kept from R9: bf16 pre-pass (swizzled LDS-image), global_load_lds staging,
// counted vmcnt(4) pipeline, compile-time cur (A/B bodies), z-via-MFMA,
// S^T orientation, Q-frags in regs, head-per-XCD grid, (256,4).

#define SEQ 2048
#define HD  64
#define BQ  128
#define BK  64

typedef __attribute__((ext_vector_type(8))) short bf16x8;
typedef __attribute__((ext_vector_type(4))) short bf16x4;
typedef __attribute__((ext_vector_type(4))) float f32x4;
typedef __attribute__((ext_vector_type(4))) unsigned u32x4;

__device__ inline unsigned packbf(float a, float b) {
    __hip_bfloat162 h = __float22bfloat162_rn(make_float2(a, b));  // a->low, b->high
    union { __hip_bfloat162 h2; unsigned u; } cv; cv.h2 = h; return cv.u;
}

__device__ inline void gload_lds16(const void* g, void* l) {
    __builtin_amdgcn_global_load_lds(
        (const __attribute__((address_space(1))) unsigned*)g,
        (__attribute__((address_space(3))) unsigned*)l, 16, 0, 0);
}

// ---------------- pre-pass: K/V -> bf16 swizzled LDS-image tiles ----------------
// K tile (64x64): kws[tile][r][g'*8..] = K[r][g*8..+7], g' = g ^ (r&7)   (16B groups)
// V tile (64x64): vws[tile][d][sg'*4..] = V[sg*4..+3][d], sg' = sg ^ (d&15) (8B groups)
__global__ __launch_bounds__(256)
void convert_kv_kernel(const float* __restrict__ kg, const float* __restrict__ vg,
                       unsigned short* __restrict__ kws, unsigned short* __restrict__ vws,
                       int* __restrict__ flags, int dozero) {
    const int head = blockIdx.x;
    const int kt   = blockIdx.y;
    const int t    = threadIdx.x;
    const size_t gbase = (size_t)head * SEQ * HD + (size_t)kt * BK * HD;
    unsigned short* ktile = kws + gbase;
    unsigned short* vtile = vws + gbase;

    if (dozero && kt == 0 && t < 8) flags[(head << 3) | t] = 0;

    {
        const int r = t >> 2, qr = t & 3;
        #pragma unroll
        for (int gg = 0; gg < 2; ++gg) {
            const int g = qr * 2 + gg;
            float4 a = *(const float4*)(kg + gbase + r * HD + g * 8);
            float4 b = *(const float4*)(kg + gbase + r * HD + g * 8 + 4);
            u32x4 pkd;
            pkd[0] = packbf(a.x, a.y); pkd[1] = packbf(a.z, a.w);
            pkd[2] = packbf(b.x, b.y); pkd[3] = packbf(b.z, b.w);
            *(u32x4*)(ktile + r * 64 + ((g ^ (r & 7)) << 3)) = pkd;
        }
    }
    {
        const int d = t & 63, sg0 = t >> 6;
        #pragma unroll
        for (int i = 0; i < 4; ++i) {
            const int sg = sg0 + i * 4;
            float v0 = vg[gbase + (sg * 4 + 0) * HD + d];
            float v1 = vg[gbase + (sg * 4 + 1) * HD + d];
            float v2 = vg[gbase + (sg * 4 + 2) * HD + d];
            float v3 = vg[gbase + (sg * 4 + 3) * HD + d];
            uint2 pkd = make_uint2(packbf(v0, v1), packbf(v2, v3));
            *(uint2*)(vtile + d * 64 + ((sg ^ (d & 15)) << 2)) = pkd;
        }
    }
}

// ---------------- main kernel ----------------
__global__ __launch_bounds__(256, 4)
void rebased_r11_kernel(const float* __restrict__ qg,
                        const unsigned short* __restrict__ kws,
                        const unsigned short* __restrict__ vws,
                        float* __restrict__ og,
                        float* __restrict__ opart,
                        float* __restrict__ zpart,
                        int* __restrict__ flags,
                        int nsplit) {
    __shared__ __align__(16) unsigned short Ks[2][BK][HD];    // swizzled image, 8KB each
    __shared__ __align__(16) unsigned short Vst[2][HD][BK];   // swizzled V^T image
    __shared__ int sOld;

    const int t    = threadIdx.x;
    const int lane = t & 63;
    const int w    = t >> 6;        // wave: q-rows [w*32, w*32+32)
    const int li   = lane & 15;
    const int qd   = lane >> 4;     // quad
    const int head = blockIdx.x;    // id%8 == head%8 -> head pinned to one XCD
    const int y    = blockIdx.y;

    // role decode: part0-heavy first, lights, then part1-heavy (backfill)
    int qt, kt0, ktN, part; bool issplit;
    if (y < nsplit)  { issplit = true;  part = 0; qt = 15 - y; kt0 = 0;      ktN = qt; }
    else if (y < 16) { issplit = false; part = 0; qt = 15 - y; kt0 = 0;      ktN = 2 * qt + 1; }
    else             { issplit = true;  part = 1; qt = 31 - y; kt0 = qt + 1; ktN = 2 * qt + 1; }
    const int niters = ktN - kt0 + 1;
    const size_t base = (size_t)head * SEQ * HD;

    // ---- Q fragments straight to registers (per-wave private; scaled) ----
    bf16x8 qf[2][2];   // [ks][mt]
    {
        const int qrow0 = qt * BQ + w * 32;
        #pragma unroll
        for (int mt = 0; mt < 2; ++mt) {
            const float* qrow = qg + base + (size_t)(qrow0 + mt * 16 + li) * HD;
            #pragma unroll
            for (int ks = 0; ks < 2; ++ks) {
                float4 a = *(const float4*)(qrow + ks * 32 + qd * 8);
                float4 b = *(const float4*)(qrow + ks * 32 + qd * 8 + 4);
                union { unsigned u[4]; bf16x8 v; } cv;
                cv.u[0] = packbf(a.x * 0.125f, a.y * 0.125f);
                cv.u[1] = packbf(a.z * 0.125f, a.w * 0.125f);
                cv.u[2] = packbf(b.x * 0.125f, b.y * 0.125f);
                cv.u[3] = packbf(b.z * 0.125f, b.w * 0.125f);
                qf[ks][mt] = cv.v;
            }
        }
    }

    // ---- DMA staging: wave w fills bytes [w*1024 + lane*16) of each 4KB half ----
    const int woff = w * 1024;
    const int goff = woff + lane * 16;
    #define STAGE(b, kt2)                                                          \
    {                                                                              \
        const char* ksrc = (const char*)(kws + base + (size_t)(kt2) * BK * HD);    \
        const char* vsrc = (const char*)(vws + base + (size_t)(kt2) * BK * HD);    \
        char* kdst = (char*)&Ks[b][0][0];                                          \
        char* vdst = (char*)&Vst[b][0][0];                                         \
        gload_lds16(ksrc + goff,        kdst + woff);                              \
        gload_lds16(ksrc + goff + 4096, kdst + woff + 4096);                       \
        gload_lds16(vsrc + goff,        vdst + woff);                              \
        gload_lds16(vsrc + goff + 4096, vdst + woff + 4096);                       \
    }

    #define WAITBAR4 asm volatile("s_waitcnt vmcnt(4)\n\ts_barrier" ::: "memory")
    #define WAITBAR0 asm volatile("s_waitcnt vmcnt(0)\n\ts_barrier" ::: "memory")
    #define ENDBAR   asm volatile("s_waitcnt lgkmcnt(0)\n\ts_barrier" ::: "memory")

    f32x4 oacc[2][4];
    f32x4 zacc[2];
    #pragma unroll
    for (int mt = 0; mt < 2; ++mt) {
        zacc[mt] = (f32x4){0.f, 0.f, 0.f, 0.f};
        #pragma unroll
        for (int nd = 0; nd < 4; ++nd) oacc[mt][nd] = (f32x4){0.f, 0.f, 0.f, 0.f};
    }
    bf16x4 onesb;
    { union { unsigned short us[4]; bf16x4 v; } o;
      o.us[0] = o.us[1] = o.us[2] = o.us[3] = 0x3F80; onesb = o.v; }

    const int qrow_min = qt * BQ + w * 32;

    #define COMPUTE(curq, ktq)                                                         \
    {                                                                                  \
        const bool active = ((ktq) * BK <= qrow_min + 31);                             \
        if (active) {                                                                  \
            const bool needmask = ((ktq) * BK + 63 > qrow_min);                        \
            _Pragma("unroll")                                                          \
            for (int h = 0; h < 2; ++h) {                                              \
                f32x4 stt[2][2];                                                       \
                _Pragma("unroll")                                                      \
                for (int n2 = 0; n2 < 2; ++n2)                                         \
                    _Pragma("unroll")                                                  \
                    for (int mt = 0; mt < 2; ++mt)                                     \
                        stt[n2][mt] = (f32x4){0.f, 0.f, 0.f, 0.f};                     \
                _Pragma("unroll")                                                      \
                for (int ks = 0; ks < 2; ++ks) {                                       \
                    bf16x8 kf[2];                                                      \
                    _Pragma("unroll")                                                  \
                    for (int n2 = 0; n2 < 2; ++n2) {                                   \
                        const int row = (h * 2 + n2) * 16 + li;                        \
                        const int grp = ((ks * 4 + qd) ^ (li & 7)) << 3;               \
                        kf[n2] = *(const bf16x8*)&Ks[curq][row][grp];                  \
                    }                                                                  \
                    _Pragma("unroll")                                                  \
                    for (int n2 = 0; n2 < 2; ++n2)                                     \
                        _Pragma("unroll")                                              \
                        for (int mt = 0; mt < 2; ++mt)                                 \
                            stt[n2][mt] = __builtin_amdgcn_mfma_f32_16x16x32_bf16(     \
                                kf[n2], qf[ks][mt], stt[n2][mt], 0, 0, 0);             \
                }                                                                      \
                unsigned pk[2][2][2];                                                  \
                _Pragma("unroll")                                                      \
                for (int n2 = 0; n2 < 2; ++n2) {                                       \
                    const int kcb = (ktq) * BK + (h * 2 + n2) * 16 + qd * 4;           \
                    _Pragma("unroll")                                                  \
                    for (int mt = 0; mt < 2; ++mt) {                                   \
                        const int qrow = qrow_min + mt * 16 + li;                      \
                        float p[4];                                                    \
                        _Pragma("unroll")                                              \
                        for (int r = 0; r < 4; ++r) {                                  \
                            float s = stt[n2][mt][r];                                  \
                            if (needmask && (kcb + r > qrow)) s = 0.f;                 \
                            p[r] = s * s;                                              \
                        }                                                              \
                        pk[n2][mt][0] = packbf(p[0], p[1]);                            \
                        pk[n2][mt][1] = packbf(p[2], p[3]);                            \
                    }                                                                  \
                }                                                                      \
                _Pragma("unroll")                                                      \
                for (int s2 = 0; s2 < 2; ++s2) {                                       \
                    bf16x4 av[2];                                                      \
                    _Pragma("unroll")                                                  \
                    for (int mt = 0; mt < 2; ++mt) {                                   \
                        union { unsigned u[2]; bf16x4 v; } cv;                         \
                        cv.u[0] = pk[s2][mt][0]; cv.u[1] = pk[s2][mt][1];              \
                        av[mt] = cv.v;                                                 \
                    }                                                                  \
                    _Pragma("unroll")                                                  \
                    for (int mt = 0; mt < 2; ++mt)                                     \
                        zacc[mt] = __builtin_amdgcn_mfma_f32_16x16x16bf16_1k(          \
                            av[mt], onesb, zacc[mt], 0, 0, 0);                         \
                    const int sg = (h * 2 + s2) * 4 + qd;                              \
                    _Pragma("unroll")                                                  \
                    for (int nd = 0; nd < 4; ++nd) {                                   \
                        const int d = nd * 16 + li;                                    \
                        bf16x4 vf = *(const bf16x4*)&Vst[curq][d][(sg ^ li) << 2];     \
                        _Pragma("unroll")                                              \
                        for (int mt = 0; mt < 2; ++mt)                                 \
                            oacc[mt][nd] = __builtin_amdgcn_mfma_f32_16x16x16bf16_1k(  \
                                av[mt], vf, oacc[mt][nd], 0, 0, 0);                    \
                    }                                                                  \
                }                                                                      \
            }                                                                          \
        }                                                                              \
    }

    // ---- k-loop: A/B bodies (compile-time cur), counted vmcnt, runtime bounds ----
    STAGE(0, kt0);
    for (int i = 0; ; i += 2) {
        const int ktA = kt0 + i;
        const bool haveB = (i + 1 < niters);
        if (haveB) { STAGE(1, ktA + 1); WAITBAR4; } else { WAITBAR0; }
        COMPUTE(0, ktA);
        if (!haveB) break;
        ENDBAR;

        const int ktB = ktA + 1;
        const bool haveC = (i + 2 < niters);
        if (haveC) { STAGE(0, ktB + 1); WAITBAR4; } else { WAITBAR0; }
        COMPUTE(1, ktB);
        if (!haveC) break;
        ENDBAR;
    }

    // ---- epilogue ----
    float* odst = og + base + (size_t)qt * BQ * HD;
    if (!issplit) {
        #pragma unroll
        for (int mt = 0; mt < 2; ++mt) {
            #pragma unroll
            for (int r = 0; r < 4; ++r) {
                float inv = 1.f / (zacc[mt][r] + 1e-6f);
                int row = w * 32 + mt * 16 + qd * 4 + r;
                #pragma unroll
                for (int nd = 0; nd < 4; ++nd)
                    odst[row * HD + nd * 16 + li] = oacc[mt][nd][r] * inv;
            }
        }
    } else {
        const int tile = (head << 3) | (qt - 8);
        float* my_o = part ? (opart + (size_t)tile * BQ * HD) : odst;
        float* my_z = zpart + ((size_t)tile * 2 + part) * BQ;

        // write own unnormalized partial
        #pragma unroll
        for (int mt = 0; mt < 2; ++mt) {
            #pragma unroll
            for (int r = 0; r < 4; ++r) {
                int row = w * 32 + mt * 16 + qd * 4 + r;
                if (li == 0) my_z[row] = zacc[mt][r];
                #pragma unroll
                for (int nd = 0; nd < 4; ++nd)
                    my_o[row * HD + nd * 16 + li] = oacc[mt][nd][r];
            }
        }

        __threadfence();       // release: partial visible before flag bump
        __syncthreads();
        if (t == 0) sOld = atomicAdd(&flags[tile], 1);
        __syncthreads();
        if (sOld == 0) return; // partner will merge

        __threadfence();       // acquire: partner's partial now visible
        const float* po = part ? odst : (opart + (size_t)tile * BQ * HD);
        const float* pz = zpart + ((size_t)tile * 2 + (1 - part)) * BQ;
        #pragma unroll
        for (int mt = 0; mt < 2; ++mt) {
            #pragma unroll
            for (int r = 0; r < 4; ++r) {
                int row = w * 32 + mt * 16 + qd * 4 + r;
                float inv = 1.f / (zacc[mt][r] + pz[row] + 1e-6f);
                #pragma unroll
                for (int nd = 0; nd < 4; ++nd)
                    odst[row * HD + nd * 16 + li] =
                        (oacc[mt][nd][r] + po[row * HD + nd * 16 + li]) * inv;
            }
        }
    }
}

extern "C" void kernel_launch(void* const* d_in, const int* in_sizes, int n_in,
                              void* d_out, int out_size, void* d_ws, size_t ws_size,
                              hipStream_t stream) {
    const float* q = (const float*)d_in[0];
    const float* k = (const float*)d_in[1];
    const float* v = (const float*)d_in[2];
    float* out = (float*)d_out;

    const size_t KVBYTES = (size_t)64 * SEQ * HD * 2;          // 16 MiB each
    unsigned short* kws = (unsigned short*)d_ws;
    unsigned short* vws = (unsigned short*)((char*)d_ws + KVBYTES);
    float* opart = (float*)((char*)d_ws + 2 * KVBYTES);        // 512 * 128*64 f32 = 16 MiB
    float* zpart = (float*)((char*)opart + (size_t)512 * BQ * HD * 4);
    int*   flags = (int*)((char*)zpart + (size_t)512 * 2 * BQ * 4);
    const size_t NEED = ((char*)(flags + 512)) - (char*)d_ws;

    const int nsplit = (ws_size >= NEED) ? 8 : 0;

    dim3 cgrid(64, 32);   // (head, k-tile)
    convert_kv_kernel<<<cgrid, dim3(256), 0, stream>>>(k, v, kws, vws, flags, nsplit ? 1 : 0);

    dim3 grid(64, nsplit ? 24 : 16);   // x=head (XCD affinity); y: part0-heavy, lights, part1
    rebased_r11_kernel<<<grid, dim3(256), 0, stream>>>(q, kws, vws, out, opart, zpart, flags, nsplit);
}

// Round 9
// 176.340 us; speedup vs baseline: 2.3289x; 2.3289x over previous
//
#include <hip/hip_runtime.h>
#include <hip/hip_bf16.h>

// ReBASED attention R12: R9 revert + uniform-branch causal mask + coalesced convert.
// R11 post-mortem: split-K's per-block __threadfence() (device-scope, L2
// writeback on non-coherent XCD L2s) thrashed the KV L2 residency (FETCH +18MB)
// and stalled all pipes (MFMA 8.6%) -> split-K via global exchange is dead here.
// R10: per-CU sum balancing null; setprio null-to-harmful in 2-barrier lockstep.
// R12 therefore reverts to the proven R9 structure (67.3us main) and cuts:
// (1) causal mask hoisted behind a wave-uniform branch -- needmask is true for
//     only ~1-2 of a wave's k-iters, so ~32 VALU inst/iter (cmp+cndmask) are
//     skipped on ~90% of iterations (VALU was the top pipe at 44%).
// (2) convert kernel's V^T write was a 128B-strided 8B scatter (64 sectors per
//     instruction, ~3.4 TB/s) -> LDS-transpose staging: coalesced reads, bf16
//     LDS tile [64][66] (padded), transposed u16 reads, contiguous 512B stores.
// Kept from R9: bf16 pre-pass workspace (swizzled LDS-image: K 16B-group
// g^=row&7, V 8B-group sg^=d&15), global_load_lds 16B staging, counted
// vmcnt(4) pipeline (never 0 in steady state), compile-time cur via kt-by-2
// unroll, z-via-MFMA (zacc C-layout == oacc), S^T orientation (QK C-layout ==
// PV A-layout), Q-frags in regs, heavy-first grid(64,16), head-per-XCD, (256,4).

#define SEQ 2048
#define HD  64
#define BQ  128
#define BK  64

typedef __attribute__((ext_vector_type(8))) short bf16x8;
typedef __attribute__((ext_vector_type(4))) short bf16x4;
typedef __attribute__((ext_vector_type(4))) float f32x4;
typedef __attribute__((ext_vector_type(4))) unsigned u32x4;

__device__ inline unsigned packbf(float a, float b) {
    __hip_bfloat162 h = __float22bfloat162_rn(make_float2(a, b));  // a->low, b->high
    union { __hip_bfloat162 h2; unsigned u; } cv; cv.h2 = h; return cv.u;
}

__device__ inline void gload_lds16(const void* g, void* l) {
    __builtin_amdgcn_global_load_lds(
        (const __attribute__((address_space(1))) unsigned*)g,
        (__attribute__((address_space(3))) unsigned*)l, 16, 0, 0);
}

// ---------------- pre-pass: K/V -> bf16 swizzled LDS-image tiles ----------------
// K tile (64x64): kws[tile][r][g'*8..] = K[r][g*8..+7], g' = g ^ (r&7)   (16B groups)
// V tile (64x64): vws[tile][d][sg'*4..] = V[sg*4..+3][d], sg' = sg ^ (d&15) (8B groups)
__global__ __launch_bounds__(256)
void convert_kv_kernel(const float* __restrict__ kg, const float* __restrict__ vg,
                       unsigned short* __restrict__ kws, unsigned short* __restrict__ vws) {
    __shared__ unsigned short vt[64][66];   // V tile bf16, padded (2-way max on reads)

    const int head = blockIdx.x;
    const int kt   = blockIdx.y;
    const int t    = threadIdx.x;
    const size_t gbase = (size_t)head * SEQ * HD + (size_t)kt * BK * HD;
    unsigned short* ktile = kws + gbase;
    unsigned short* vtile = vws + gbase;

    // ---- K: coalesced read, swizzled 16B-group write (16B stores) ----
    {
        const int r = t >> 2, qr = t & 3;
        #pragma unroll
        for (int gg = 0; gg < 2; ++gg) {
            const int g = qr * 2 + gg;
            float4 a = *(const float4*)(kg + gbase + r * HD + g * 8);
            float4 b = *(const float4*)(kg + gbase + r * HD + g * 8 + 4);
            u32x4 pkd;
            pkd[0] = packbf(a.x, a.y); pkd[1] = packbf(a.z, a.w);
            pkd[2] = packbf(b.x, b.y); pkd[3] = packbf(b.z, b.w);
            *(u32x4*)(ktile + r * 64 + ((g ^ (r & 7)) << 3)) = pkd;
        }
    }

    // ---- V: coalesced read -> bf16 LDS -> transposed read -> contiguous write ----
    {
        const int vrow = t >> 5;           // 0..7
        const int vd2  = (t & 31) * 2;     // even d
        #pragma unroll
        for (int p = 0; p < 8; ++p) {
            const int row = p * 8 + vrow;
            float2 v = *(const float2*)(vg + gbase + row * HD + vd2);
            *(unsigned*)&vt[row][vd2] = packbf(v.x, v.y);
        }
    }
    __syncthreads();
    {
        const int sg = t & 15;             // logical 8B group (4 rows)
        const int d0 = t >> 4;             // 0..15
        #pragma unroll
        for (int p = 0; p < 4; ++p) {
            const int d = p * 16 + d0;
            unsigned lo = (unsigned)vt[sg * 4 + 0][d] | ((unsigned)vt[sg * 4 + 1][d] << 16);
            unsigned hi = (unsigned)vt[sg * 4 + 2][d] | ((unsigned)vt[sg * 4 + 3][d] << 16);
            // 16 lanes per d-group cover a contiguous 128B row; 4 rows/instr = 512B
            *(uint2*)(vtile + d * 64 + ((sg ^ (d & 15)) << 2)) = make_uint2(lo, hi);
        }
    }
}

// ---------------- main kernel ----------------
__global__ __launch_bounds__(256, 4)
void rebased_r12_kernel(const float* __restrict__ qg,
                        const unsigned short* __restrict__ kws,
                        const unsigned short* __restrict__ vws,
                        float* __restrict__ og) {
    __shared__ __align__(16) unsigned short Ks[2][BK][HD];    // swizzled image, 8KB each
    __shared__ __align__(16) unsigned short Vst[2][HD][BK];   // swizzled V^T image

    const int t    = threadIdx.x;
    const int lane = t & 63;
    const int w    = t >> 6;        // wave: q-rows [w*32, w*32+32)
    const int li   = lane & 15;
    const int qd   = lane >> 4;     // quad
    const int head = blockIdx.x;    // id%8 == head%8 -> head pinned to one XCD
    const int qt   = 15 - blockIdx.y;  // heavy-first (LPT)
    const int ktmax = 2 * qt + 1;      // odd -> iteration count even
    const size_t base = (size_t)head * SEQ * HD;

    // ---- Q fragments straight to registers (per-wave private; scaled) ----
    bf16x8 qf[2][2];   // [ks][mt]
    {
        const int qrow0 = qt * BQ + w * 32;
        #pragma unroll
        for (int mt = 0; mt < 2; ++mt) {
            const float* qrow = qg + base + (size_t)(qrow0 + mt * 16 + li) * HD;
            #pragma unroll
            for (int ks = 0; ks < 2; ++ks) {
                float4 a = *(const float4*)(qrow + ks * 32 + qd * 8);
                float4 b = *(const float4*)(qrow + ks * 32 + qd * 8 + 4);
                union { unsigned u[4]; bf16x8 v; } cv;
                cv.u[0] = packbf(a.x * 0.125f, a.y * 0.125f);
                cv.u[1] = packbf(a.z * 0.125f, a.w * 0.125f);
                cv.u[2] = packbf(b.x * 0.125f, b.y * 0.125f);
                cv.u[3] = packbf(b.z * 0.125f, b.w * 0.125f);
                qf[ks][mt] = cv.v;
            }
        }
    }

    // ---- DMA staging: wave w fills bytes [w*1024 + lane*16) of each 4KB half ----
    const int woff = w * 1024;
    const int goff = woff + lane * 16;
    #define STAGE(b, kt2)                                                          \
    {                                                                              \
        const char* ksrc = (const char*)(kws + base + (size_t)(kt2) * BK * HD);    \
        const char* vsrc = (const char*)(vws + base + (size_t)(kt2) * BK * HD);    \
        char* kdst = (char*)&Ks[b][0][0];                                          \
        char* vdst = (char*)&Vst[b][0][0];                                         \
        gload_lds16(ksrc + goff,        kdst + woff);                              \
        gload_lds16(ksrc + goff + 4096, kdst + woff + 4096);                       \
        gload_lds16(vsrc + goff,        vdst + woff);                              \
        gload_lds16(vsrc + goff + 4096, vdst + woff + 4096);                       \
    }

    // pipeline barriers: counted vmcnt, single-asm so nothing crosses
    #define WAITBAR4 asm volatile("s_waitcnt vmcnt(4)\n\ts_barrier" ::: "memory")
    #define WAITBAR0 asm volatile("s_waitcnt vmcnt(0)\n\ts_barrier" ::: "memory")
    #define ENDBAR   asm volatile("s_waitcnt lgkmcnt(0)\n\ts_barrier" ::: "memory")

    f32x4 oacc[2][4];
    f32x4 zacc[2];
    #pragma unroll
    for (int mt = 0; mt < 2; ++mt) {
        zacc[mt] = (f32x4){0.f, 0.f, 0.f, 0.f};
        #pragma unroll
        for (int nd = 0; nd < 4; ++nd) oacc[mt][nd] = (f32x4){0.f, 0.f, 0.f, 0.f};
    }
    bf16x4 onesb;
    { union { unsigned short us[4]; bf16x4 v; } o;
      o.us[0] = o.us[1] = o.us[2] = o.us[3] = 0x3F80; onesb = o.v; }

    const int qrow_min = qt * BQ + w * 32;

    #define COMPUTE(curq, ktq)                                                         \
    {                                                                                  \
        const bool active = ((ktq) * BK <= qrow_min + 31);                             \
        if (active) {                                                                  \
            const bool needmask = ((ktq) * BK + 63 > qrow_min);                        \
            _Pragma("unroll")                                                          \
            for (int h = 0; h < 2; ++h) {                                              \
                f32x4 stt[2][2];                                                       \
                _Pragma("unroll")                                                      \
                for (int n2 = 0; n2 < 2; ++n2)                                         \
                    _Pragma("unroll")                                                  \
                    for (int mt = 0; mt < 2; ++mt)                                     \
                        stt[n2][mt] = (f32x4){0.f, 0.f, 0.f, 0.f};                     \
                _Pragma("unroll")                                                      \
                for (int ks = 0; ks < 2; ++ks) {                                       \
                    bf16x8 kf[2];                                                      \
                    _Pragma("unroll")                                                  \
                    for (int n2 = 0; n2 < 2; ++n2) {                                   \
                        const int row = (h * 2 + n2) * 16 + li;                        \
                        const int grp = ((ks * 4 + qd) ^ (li & 7)) << 3;               \
                        kf[n2] = *(const bf16x8*)&Ks[curq][row][grp];                  \
                    }                                                                  \
                    _Pragma("unroll")                                                  \
                    for (int n2 = 0; n2 < 2; ++n2)                                     \
                        _Pragma("unroll")                                              \
                        for (int mt = 0; mt < 2; ++mt)                                 \
                            stt[n2][mt] = __builtin_amdgcn_mfma_f32_16x16x32_bf16(     \
                                kf[n2], qf[ks][mt], stt[n2][mt], 0, 0, 0);             \
                }                                                                      \
                /* causal mask: wave-uniform branch, taken on <=2 iters per wave */    \
                if (needmask) {                                                        \
                    _Pragma("unroll")                                                  \
                    for (int n2 = 0; n2 < 2; ++n2) {                                   \
                        const int kcb = (ktq) * BK + (h * 2 + n2) * 16 + qd * 4;       \
                        _Pragma("unroll")                                              \
                        for (int mt = 0; mt < 2; ++mt) {                               \
                            const int qrow = qrow_min + mt * 16 + li;                  \
                            _Pragma("unroll")                                          \
                            for (int r = 0; r < 4; ++r)                                \
                                if (kcb + r > qrow) stt[n2][mt][r] = 0.f;              \
                        }                                                              \
                    }                                                                  \
                }                                                                      \
                unsigned pk[2][2][2];                                                  \
                _Pragma("unroll")                                                      \
                for (int n2 = 0; n2 < 2; ++n2) {                                       \
                    _Pragma("unroll")                                                  \
                    for (int mt = 0; mt < 2; ++mt) {                                   \
                        float p[4];                                                    \
                        _Pragma("unroll")                                              \
                        for (int r = 0; r < 4; ++r) {                                  \
                            float s = stt[n2][mt][r];                                  \
                            p[r] = s * s;                                              \
                        }                                                              \
                        pk[n2][mt][0] = packbf(p[0], p[1]);                            \
                        pk[n2][mt][1] = packbf(p[2], p[3]);                            \
                    }                                                                  \
                }                                                                      \
                _Pragma("unroll")                                                      \
                for (int s2 = 0; s2 < 2; ++s2) {                                       \
                    bf16x4 av[2];                                                      \
                    _Pragma("unroll")                                                  \
                    for (int mt = 0; mt < 2; ++mt) {                                   \
                        union { unsigned u[2]; bf16x4 v; } cv;                         \
                        cv.u[0] = pk[s2][mt][0]; cv.u[1] = pk[s2][mt][1];              \
                        av[mt] = cv.v;                                                 \
                    }                                                                  \
                    _Pragma("unroll")                                                  \
                    for (int mt = 0; mt < 2; ++mt)                                     \
                        zacc[mt] = __builtin_amdgcn_mfma_f32_16x16x16bf16_1k(          \
                            av[mt], onesb, zacc[mt], 0, 0, 0);                         \
                    const int sg = (h * 2 + s2) * 4 + qd;                              \
                    _Pragma("unroll")                                                  \
                    for (int nd = 0; nd < 4; ++nd) {                                   \
                        const int d = nd * 16 + li;                                    \
                        bf16x4 vf = *(const bf16x4*)&Vst[curq][d][(sg ^ li) << 2];     \
                        _Pragma("unroll")                                              \
                        for (int mt = 0; mt < 2; ++mt)                                 \
                            oacc[mt][nd] = __builtin_amdgcn_mfma_f32_16x16x16bf16_1k(  \
                                av[mt], vf, oacc[mt][nd], 0, 0, 0);                    \
                    }                                                                  \
                }                                                                      \
            }                                                                          \
        }                                                                              \
    }

    STAGE(0, 0);   // 4 loads in flight

    for (int kt = 0; kt <= ktmax; kt += 2) {
        // ---- body A: cur=0, iter kt (kt even, ktmax odd -> kt < ktmax always) ----
        STAGE(1, kt + 1);     // outstanding: 8
        WAITBAR4;             // stage(kt) landed for this wave; barrier -> for all waves
        COMPUTE(0, kt);
        ENDBAR;               // all waves done reading buf0 before its next overwrite

        // ---- body B: cur=1, iter kt+1 ----
        if (kt + 1 < ktmax) { STAGE(0, kt + 2); WAITBAR4; }
        else                { WAITBAR0; }                    // final tile: full drain
        COMPUTE(1, kt + 1);
        if (kt + 1 < ktmax) { ENDBAR; }
    }

    // ---- epilogue: zacc has the same C-layout as oacc -> local divide, no shuffles ----
    float* odst = og + base + (size_t)qt * BQ * HD;
    #pragma unroll
    for (int mt = 0; mt < 2; ++mt) {
        #pragma unroll
        for (int r = 0; r < 4; ++r) {
            float inv = 1.f / (zacc[mt][r] + 1e-6f);
            int row = w * 32 + mt * 16 + qd * 4 + r;
            #pragma unroll
            for (int nd = 0; nd < 4; ++nd)
                odst[row * HD + nd * 16 + li] = oacc[mt][nd][r] * inv;
        }
    }
}

extern "C" void kernel_launch(void* const* d_in, const int* in_sizes, int n_in,
                              void* d_out, int out_size, void* d_ws, size_t ws_size,
                              hipStream_t stream) {
    const float* q = (const float*)d_in[0];
    const float* k = (const float*)d_in[1];
    const float* v = (const float*)d_in[2];
    float* out = (float*)d_out;

    unsigned short* kws = (unsigned short*)d_ws;
    unsigned short* vws = kws + (size_t)64 * SEQ * HD;   // +16MB; total ws use 32MB

    dim3 cgrid(64, 32);   // (head, k-tile)
    convert_kv_kernel<<<cgrid, dim3(256), 0, stream>>>(k, v, kws, vws);

    dim3 grid(64, 16);    // x=head (XCD affinity), y: heavy q-tiles first
    rebased_r12_kernel<<<grid, dim3(256), 0, stream>>>(q, kws, vws, out);
}